// Round 2
// baseline (1647.107 us; speedup 1.0000x reference)
//
#include <hip/hip_runtime.h>

#define BB    32
#define TTOT  48
#define TT    24
#define NN    1000
#define FF    16
#define CCH   17      // F+1
#define HID   64
#define EMB   8
#define NHEADS 4
#define DDIM  16      // HID/HEADS
#define DEG   16

#define SH    68      // padded row stride for [24][HID] LDS tiles (16B aligned, bank-offset 4)
#define SC    20      // padded row stride for [24][C] tiles: col0 = y, cols 4..19 = X[0..15]
#define SROW  25      // score row stride
#define SHEAD 600     // score head stride (24*25)

__device__ __forceinline__ float sigmoidf(float x) {
    return 1.0f / (1.0f + __expf(-x));
}

// dst[t][j] = bias[j] + sum_m src[t][m] * W[m][j], t in {g, g+4, ..., g+20}
// src rows stride SH, float4-vectorized over m; dst rows stride SH.
__device__ __forceinline__ void mm64v(const float* __restrict__ W,
                                      const float* __restrict__ bias,
                                      const float* __restrict__ src,
                                      float* __restrict__ dst,
                                      int j, int g)
{
    float acc[6];
    const float bb = bias[j];
#pragma unroll
    for (int i = 0; i < 6; ++i) acc[i] = bb;
#pragma unroll 4
    for (int m = 0; m < HID; m += 4) {
        const float w0 = W[(m + 0) * HID + j];
        const float w1 = W[(m + 1) * HID + j];
        const float w2 = W[(m + 2) * HID + j];
        const float w3 = W[(m + 3) * HID + j];
#pragma unroll
        for (int i = 0; i < 6; ++i) {
            const float4 s4 = *(const float4*)&src[(g + 4 * i) * SH + m];
            acc[i] += s4.x * w0 + s4.y * w1 + s4.z * w2 + s4.w * w3;
        }
    }
#pragma unroll
    for (int i = 0; i < 6; ++i) dst[(g + 4 * i) * SH + j] = acc[i];
}

extern "C" __global__ __launch_bounds__(256, 4)
void encoder_node(const float* __restrict__ X, const float* __restrict__ Y,
                  const int* __restrict__ esrc, const float* __restrict__ ew,
                  const float* __restrict__ pos,
                  const float* __restrict__ W_rel, const float* __restrict__ b_rel,
                  const float* __restrict__ W_root,
                  const float* __restrict__ W_fc, const float* __restrict__ b_fc,
                  const float* __restrict__ Wq, const float* __restrict__ bq,
                  const float* __restrict__ Wk, const float* __restrict__ bk,
                  const float* __restrict__ Wv, const float* __restrict__ bv,
                  const float* __restrict__ Wo, const float* __restrict__ bo,
                  const float* __restrict__ Wm, const float* __restrict__ bm,
                  float* __restrict__ out)
{
    // LDS layout (floats), heavy aliasing:
    //   [0,480)    xn   [24][20]      (dead after fc)
    //   [480,960)  agg  [24][20]      (dead after rel)
    //   [960,2592) z    [24][68]      (dead after qkv)
    //   [0,2400)   s    [4][24][25]   (alias xn+agg+z; live scores..ctx)
    //   [2592,4224) h   [24][68]      (ctx aliases h after fc)
    //   [4224,5856) q   [24][68]      (o0 aliases q after scores)
    //   [5856,7488) k   [24][68]
    //   [7488,9120) v   [24][68]
    __shared__ float buf[9120];         // 36480 B -> 4 blocks/CU
    __shared__ float w_s[DEG];
    __shared__ int   src_s[DEG];

    float* __restrict__ xn  = buf;
    float* __restrict__ agg = buf + 480;
    float* __restrict__ z   = buf + 960;
    float* __restrict__ sS  = buf;          // alias
    float* __restrict__ hS  = buf + 2592;
    float* __restrict__ qS  = buf + 4224;
    float* __restrict__ kS  = buf + 5856;
    float* __restrict__ vS  = buf + 7488;
    float* __restrict__ ctxS = hS;          // alias
    float* __restrict__ oS   = qS;          // alias

    const int u   = blockIdx.x;
    const int b   = u / NN;
    const int n   = u - b * NN;
    const int tid = threadIdx.x;

    if (tid < DEG) {
        src_s[tid] = esrc[u * DEG + tid] - b * NN;  // local neighbor index
        w_s[tid]   = ew[u * DEG + tid];
    }
    // own feature row: xn[t][0]=y, xn[t][4+f]=X[f]
    for (int e = tid; e < TT * CCH; e += 256) {
        const int t = e / CCH, c = e - t * CCH;
        const int sc = (c == 0) ? 0 : (3 + c);
        xn[t * SC + sc] = (c == 0) ? Y[(b * TTOT + t) * NN + n]
                                   : X[((size_t)(b * TTOT + t) * NN + n) * FF + (c - 1)];
    }
    __syncthreads();

    // weighted neighbor aggregation
    for (int e = tid; e < TT * CCH; e += 256) {
        const int t = e / CCH, c = e - t * CCH;
        const int sc = (c == 0) ? 0 : (3 + c);
        float a = 0.f;
#pragma unroll
        for (int kE = 0; kE < DEG; ++kE) {
            const int ns = src_s[kE];
            const float xv = (c == 0)
                ? Y[(b * TTOT + t) * NN + ns]
                : X[((size_t)(b * TTOT + t) * NN + ns) * FF + (c - 1)];
            a += w_s[kE] * xv;
        }
        agg[t * SC + sc] = a;
    }
    __syncthreads();

    const int j = tid & 63;
    const int g = tid >> 6;   // wave id; rows g, g+4, ..., g+20

    // h = sigmoid(agg @ W_rel + b_rel + xn @ W_root)
    {
        float acc[6];
        const float br = b_rel[j];
#pragma unroll
        for (int i = 0; i < 6; ++i) acc[i] = br;
        {   // c = 0 (y channel)
            const float wr = W_rel[j], wt = W_root[j];
#pragma unroll
            for (int i = 0; i < 6; ++i) {
                const int t = g + 4 * i;
                acc[i] += agg[t * SC] * wr + xn[t * SC] * wt;
            }
        }
#pragma unroll
        for (int f4 = 0; f4 < FF; f4 += 4) {   // c = 1+f4 .. 4+f4
            float wr[4], wt[4];
#pragma unroll
            for (int q2 = 0; q2 < 4; ++q2) {
                wr[q2] = W_rel[(1 + f4 + q2) * HID + j];
                wt[q2] = W_root[(1 + f4 + q2) * HID + j];
            }
#pragma unroll
            for (int i = 0; i < 6; ++i) {
                const int t = g + 4 * i;
                const float4 a4 = *(const float4*)&agg[t * SC + 4 + f4];
                const float4 x4 = *(const float4*)&xn[t * SC + 4 + f4];
                acc[i] += a4.x * wr[0] + a4.y * wr[1] + a4.z * wr[2] + a4.w * wr[3]
                        + x4.x * wt[0] + x4.y * wt[1] + x4.z * wt[2] + x4.w * wt[3];
            }
        }
#pragma unroll
        for (int i = 0; i < 6; ++i) hS[(g + 4 * i) * SH + j] = sigmoidf(acc[i]);
    }
    __syncthreads();

    // z = concat(pos, h, X, y) @ W_fc + b_fc
    {
        float acc[6];
        const float bf = b_fc[j];
#pragma unroll
        for (int i = 0; i < 6; ++i) acc[i] = bf;
#pragma unroll
        for (int e4 = 0; e4 < EMB; e4 += 4) {
            float w[4];
#pragma unroll
            for (int q2 = 0; q2 < 4; ++q2) w[q2] = W_fc[(e4 + q2) * HID + j];
#pragma unroll
            for (int i = 0; i < 6; ++i) {
                const float4 p4 = *(const float4*)&pos[(g + 4 * i) * EMB + e4];
                acc[i] += p4.x * w[0] + p4.y * w[1] + p4.z * w[2] + p4.w * w[3];
            }
        }
#pragma unroll 4
        for (int m = 0; m < HID; m += 4) {
            float w[4];
#pragma unroll
            for (int q2 = 0; q2 < 4; ++q2) w[q2] = W_fc[(EMB + m + q2) * HID + j];
#pragma unroll
            for (int i = 0; i < 6; ++i) {
                const float4 h4 = *(const float4*)&hS[(g + 4 * i) * SH + m];
                acc[i] += h4.x * w[0] + h4.y * w[1] + h4.z * w[2] + h4.w * w[3];
            }
        }
#pragma unroll
        for (int f4 = 0; f4 < FF; f4 += 4) {
            float w[4];
#pragma unroll
            for (int q2 = 0; q2 < 4; ++q2) w[q2] = W_fc[(EMB + HID + f4 + q2) * HID + j];
#pragma unroll
            for (int i = 0; i < 6; ++i) {
                const float4 x4 = *(const float4*)&xn[(g + 4 * i) * SC + 4 + f4];
                acc[i] += x4.x * w[0] + x4.y * w[1] + x4.z * w[2] + x4.w * w[3];
            }
        }
        {
            const float w = W_fc[(EMB + HID + FF) * HID + j];
#pragma unroll
            for (int i = 0; i < 6; ++i) acc[i] += xn[(g + 4 * i) * SC] * w;
        }
#pragma unroll
        for (int i = 0; i < 6; ++i) z[(g + 4 * i) * SH + j] = acc[i];
    }
    __syncthreads();

    // fused q, k, v = z @ {Wq,Wk,Wv} + bias
    {
        float aq[6], ak[6], av[6];
        const float bq_ = bq[j], bk_ = bk[j], bv_ = bv[j];
#pragma unroll
        for (int i = 0; i < 6; ++i) { aq[i] = bq_; ak[i] = bk_; av[i] = bv_; }
#pragma unroll 2
        for (int m = 0; m < HID; m += 4) {
            float wq_[4], wk_[4], wv_[4];
#pragma unroll
            for (int q2 = 0; q2 < 4; ++q2) {
                wq_[q2] = Wq[(m + q2) * HID + j];
                wk_[q2] = Wk[(m + q2) * HID + j];
                wv_[q2] = Wv[(m + q2) * HID + j];
            }
#pragma unroll
            for (int i = 0; i < 6; ++i) {
                const float4 z4 = *(const float4*)&z[(g + 4 * i) * SH + m];
                aq[i] += z4.x * wq_[0] + z4.y * wq_[1] + z4.z * wq_[2] + z4.w * wq_[3];
                ak[i] += z4.x * wk_[0] + z4.y * wk_[1] + z4.z * wk_[2] + z4.w * wk_[3];
                av[i] += z4.x * wv_[0] + z4.y * wv_[1] + z4.z * wv_[2] + z4.w * wv_[3];
            }
        }
#pragma unroll
        for (int i = 0; i < 6; ++i) {
            const int t = g + 4 * i;
            qS[t * SH + j] = aq[i];
            kS[t * SH + j] = ak[i];
            vS[t * SH + j] = av[i];
        }
    }
    __syncthreads();

    // scores: wave g handles head g; lanes own (r,c2) pairs. Writes sS (aliases xn/agg/z).
    {
        const int hh = g;
        for (int p = j; p < TT * TT; p += 64) {
            const int r  = p / TT;
            const int c2 = p - r * TT;
            float a = 0.f;
#pragma unroll
            for (int d4 = 0; d4 < DDIM; d4 += 4) {
                const float4 q4 = *(const float4*)&qS[r  * SH + hh * DDIM + d4];
                const float4 k4 = *(const float4*)&kS[c2 * SH + hh * DDIM + d4];
                a += q4.x * k4.x + q4.y * k4.y + q4.z * k4.z + q4.w * k4.w;
            }
            sS[hh * SHEAD + r * SROW + c2] = a * 0.25f;
        }
    }
    __syncthreads();

    // softmax over last dim (96 rows, one thread each)
    if (tid < NHEADS * TT) {
        const int hh = tid / TT, r = tid - hh * TT;
        float* row = sS + hh * SHEAD + r * SROW;
        float mx = row[0];
        for (int i2 = 1; i2 < TT; ++i2) mx = fmaxf(mx, row[i2]);
        float sm = 0.f;
        for (int i2 = 0; i2 < TT; ++i2) { const float ev = __expf(row[i2] - mx); row[i2] = ev; sm += ev; }
        const float inv = 1.f / sm;
        for (int i2 = 0; i2 < TT; ++i2) row[i2] *= inv;
    }
    __syncthreads();

    // ctx[t][j] = sum_jj s[hh][t][jj] * v[jj][j]   (hh = j>>4); ctx aliases h
    {
        const int hh = j >> 4;
        float acc[6];
#pragma unroll
        for (int i = 0; i < 6; ++i) acc[i] = 0.f;
#pragma unroll 4
        for (int jj = 0; jj < TT; ++jj) {
            const float vv = vS[jj * SH + j];
#pragma unroll
            for (int i = 0; i < 6; ++i)
                acc[i] += sS[hh * SHEAD + (g + 4 * i) * SROW + jj] * vv;
        }
#pragma unroll
        for (int i = 0; i < 6; ++i) ctxS[(g + 4 * i) * SH + j] = acc[i];
    }
    __syncthreads();

    // o0 = ctx @ Wo + bo   (o0 aliases q)
    mm64v(Wo, bo, ctxS, oS, j, g);
    __syncthreads();

    // out = o0 @ W_mlp + b_mlp
    {
        float acc[6];
        const float bb2 = bm[j];
#pragma unroll
        for (int i = 0; i < 6; ++i) acc[i] = bb2;
#pragma unroll 4
        for (int m = 0; m < HID; m += 4) {
            const float w0 = Wm[(m + 0) * HID + j];
            const float w1 = Wm[(m + 1) * HID + j];
            const float w2 = Wm[(m + 2) * HID + j];
            const float w3 = Wm[(m + 3) * HID + j];
#pragma unroll
            for (int i = 0; i < 6; ++i) {
                const float4 s4 = *(const float4*)&oS[(g + 4 * i) * SH + m];
                acc[i] += s4.x * w0 + s4.y * w1 + s4.z * w2 + s4.w * w3;
            }
        }
#pragma unroll
        for (int i = 0; i < 6; ++i) {
            const int t = g + 4 * i;
            out[((size_t)(b * TT + t) * NN + n) * HID + j] = acc[i];
        }
    }
}

extern "C" void kernel_launch(void* const* d_in, const int* in_sizes, int n_in,
                              void* d_out, int out_size, void* d_ws, size_t ws_size,
                              hipStream_t stream)
{
    const float* X     = (const float*)d_in[0];
    const float* Y     = (const float*)d_in[1];
    const int*   esrc  = (const int*)d_in[2];
    const float* ew    = (const float*)d_in[4];
    const float* pos   = (const float*)d_in[5];
    const float* W_rel = (const float*)d_in[6];
    const float* b_rel = (const float*)d_in[7];
    const float* W_root= (const float*)d_in[8];
    const float* W_fc  = (const float*)d_in[9];
    const float* b_fc  = (const float*)d_in[10];
    const float* Wq    = (const float*)d_in[11];
    const float* bq    = (const float*)d_in[12];
    const float* Wk    = (const float*)d_in[13];
    const float* bk    = (const float*)d_in[14];
    const float* Wv    = (const float*)d_in[15];
    const float* bv    = (const float*)d_in[16];
    const float* Wo    = (const float*)d_in[17];
    const float* bo    = (const float*)d_in[18];
    const float* Wm    = (const float*)d_in[19];
    const float* bm    = (const float*)d_in[20];
    float* out = (float*)d_out;

    encoder_node<<<dim3(BB * NN), dim3(256), 0, stream>>>(
        X, Y, esrc, ew, pos, W_rel, b_rel, W_root, W_fc, b_fc,
        Wq, bq, Wk, bk, Wv, bv, Wo, bo, Wm, bm, out);
}

// Round 3
// 645.695 us; speedup vs baseline: 2.5509x; 2.5509x over previous
//
#include <hip/hip_runtime.h>

typedef __attribute__((ext_vector_type(8))) short bf16x8;
typedef __attribute__((ext_vector_type(4))) float f32x4;

#define BB    32
#define TTOT  48
#define TT    24
#define NN    1000
#define FF    16
#define CCH   17
#define HID   64
#define EMB   8
#define DEG   16

#define SREL  72      // u16 stride for K=64 A-tiles (rel/z/ctx/o): bank-spread, 16B-aligned rows
#define SFC   104     // u16 stride for K=96 A-tile (fc)

// d_ws layout (u16 elements): each weight transposed Wt[c][k] (B^T), hi tile then lo tile
#define OFF_REL 0         // [64][64] combined [W_rel;W_root;0-pad]
#define OFF_FC  8192      // [64][96]
#define OFF_Q   20480
#define OFF_K   28672
#define OFF_V   36864
#define OFF_O   45056
#define OFF_M   53248
#define WS_U16  61440

__device__ __forceinline__ void split_bf16(float x, unsigned short& hi, unsigned short& lo) {
    const unsigned int bits = __float_as_uint(x);
    hi = (unsigned short)(bits >> 16);                       // truncate to bf16
    const float lf = x - __uint_as_float(bits & 0xFFFF0000u); // exact residual
    lo = (unsigned short)(__float_as_uint(lf) >> 16);
}

__device__ __forceinline__ f32x4 mfma16(bf16x8 a, bf16x8 b, f32x4 c) {
    return __builtin_amdgcn_mfma_f32_16x16x32_bf16(a, b, c, 0, 0, 0);
}

// acc[mt] += A[mt*16.., :K] @ W[:, colw..colw+15]  (split bf16: aH*bH + aH*bL + aL*bH)
__device__ __forceinline__ void gemm_frag(const unsigned short* __restrict__ AH,
                                          const unsigned short* __restrict__ AL,
                                          const int SA,
                                          const unsigned short* __restrict__ WB, // hi; lo at +64*KPw
                                          const int KPw, const int KT,
                                          const int mycol, const int lr, const int lg,
                                          f32x4 acc[2])
{
    const unsigned short* wrow = WB + (size_t)mycol * KPw;
    for (int kt = 0; kt < KT; ++kt) {
        const int k0 = kt * 32 + lg * 8;
        const bf16x8 bH = *(const bf16x8*)(wrow + k0);
        const bf16x8 bL = *(const bf16x8*)(wrow + (size_t)64 * KPw + k0);
#pragma unroll
        for (int mt = 0; mt < 2; ++mt) {
            const int row = mt * 16 + lr;
            const bf16x8 aH = *(const bf16x8*)(AH + row * SA + k0);
            const bf16x8 aL = *(const bf16x8*)(AL + row * SA + k0);
            acc[mt] = mfma16(aL, bH, acc[mt]);
            acc[mt] = mfma16(aH, bL, acc[mt]);
            acc[mt] = mfma16(aH, bH, acc[mt]);
        }
    }
}

// ---- weight prep: fp32 -> transposed bf16 hi/lo in d_ws (runs every launch) ----
extern "C" __global__ __launch_bounds__(256)
void prep_w(const float* __restrict__ W_rel, const float* __restrict__ W_root,
            const float* __restrict__ W_fc,  const float* __restrict__ Wq,
            const float* __restrict__ Wk,    const float* __restrict__ Wv,
            const float* __restrict__ Wo,    const float* __restrict__ Wm,
            unsigned short* __restrict__ ws)
{
    const int id = blockIdx.x * 256 + threadIdx.x;   // [0, 30720)
    int off, kp, c, k;
    float val;
    if (id < 4096) {                         // rel-combined, Kp=64
        off = OFF_REL; kp = 64; c = id >> 6; k = id & 63;
        val = (k < 17) ? W_rel[k * HID + c] : ((k < 34) ? W_root[(k - 17) * HID + c] : 0.f);
    } else if (id < 10240) {                 // fc, Kp=96
        const int i = id - 4096; off = OFF_FC; kp = 96; c = i / 96; k = i - c * 96;
        val = (k < 89) ? W_fc[k * HID + c] : 0.f;
    } else {
        const int seg = (id - 10240) >> 12;  // 0..4 -> q,k,v,o,m
        const int i = (id - 10240) & 4095; kp = 64; c = i >> 6; k = i & 63;
        const float* W;
        switch (seg) {
            case 0: off = OFF_Q; W = Wq; break;
            case 1: off = OFF_K; W = Wk; break;
            case 2: off = OFF_V; W = Wv; break;
            case 3: off = OFF_O; W = Wo; break;
            default: off = OFF_M; W = Wm; break;
        }
        val = W[k * HID + c];
    }
    unsigned short hi, lo; split_bf16(val, hi, lo);
    ws[off + c * kp + k] = hi;
    ws[off + 64 * kp + c * kp + k] = lo;
}

// ---- main fused kernel: one block per node ----
extern "C" __global__ __launch_bounds__(256)
void encoder_mfma(const float* __restrict__ X, const float* __restrict__ Y,
                  const int* __restrict__ esrc, const float* __restrict__ ew,
                  const float* __restrict__ pos,
                  const float* __restrict__ b_rel, const float* __restrict__ b_fc,
                  const float* __restrict__ bq, const float* __restrict__ bk,
                  const float* __restrict__ bv, const float* __restrict__ bo,
                  const float* __restrict__ bm,
                  const unsigned short* __restrict__ ws,
                  float* __restrict__ out)
{
    // u16 smem carve (aliased):
    //  [0,4608)      relA hi/lo [32][72]   -> later zA, then ctxA
    //  [4608,11264)  fcA hi/lo  [32][104]  -> later sS (f32 4x24x25), then oA hi/lo
    //  [11264,21056) qS,kS,vS f32 [24][68] each
    __shared__ unsigned short smem[21056];
    __shared__ float w_s[DEG];
    __shared__ int   src_s[DEG];

    unsigned short* relA_hi = smem;
    unsigned short* relA_lo = smem + 2304;
    unsigned short* fcA_hi  = smem + 4608;
    unsigned short* fcA_lo  = smem + 7936;
    float* sS = (float*)(smem + 4608);            // 2400 floats
    unsigned short* oA_hi = smem + 4608;
    unsigned short* oA_lo = smem + 6912;
    float* qS = (float*)(smem + 11264);
    float* kS = qS + TT * 68;
    float* vS = qS + 2 * TT * 68;

    const int u = blockIdx.x, b = u / NN, n = u - b * NN;
    const int tid  = threadIdx.x;
    const int w    = tid >> 6;          // wave id: N-slice for MFMA, head for scores, row-group for ctx
    const int lane = tid & 63;
    const int lr   = tid & 15;
    const int lg   = (tid >> 4) & 3;
    const int mycol = 16 * w + lr;      // this lane's output column in all GEMMs

    const float brel_v = b_rel[mycol];
    const float bfc_v  = b_fc[mycol];
    const float bq_v = bq[mycol], bk_v = bk[mycol], bv_v = bv[mycol];
    const float bo_v = bo[mycol], bm_v = bm[mycol];

    if (tid < DEG) {
        src_s[tid] = esrc[u * DEG + tid] - b * NN;
        w_s[tid]   = ew[u * DEG + tid];
    }
    // pos -> fcA cols 0..7
    for (int p = tid; p < TT * EMB; p += 256) {
        const int t = p >> 3, e = p & 7;
        unsigned short hi, lo; split_bf16(pos[p], hi, lo);
        fcA_hi[t * SFC + e] = hi; fcA_lo[t * SFC + e] = lo;
    }
    // zero pads: relA cols 34..63, fcA cols 89..95 (rows 0..23) — B pads are zeroed in ws
    for (int p = tid; p < TT * 30; p += 256) {
        const int t = p / 30, c = 34 + (p - t * 30);
        relA_hi[t * SREL + c] = 0; relA_lo[t * SREL + c] = 0;
    }
    for (int p = tid; p < TT * 7; p += 256) {
        const int t = p / 7, c = 89 + (p - t * 7);
        fcA_hi[t * SFC + c] = 0; fcA_lo[t * SFC + c] = 0;
    }
    __syncthreads();

    // gather: own features + weighted neighbor aggregation -> relA (bf16 hi/lo) + fcA X/y cols
    for (int e = tid; e < TT * CCH; e += 256) {
        const int t = e / CCH, c = e - t * CCH;
        const size_t rowb = (size_t)(b * TTOT + t) * NN;
        const float* p = (c == 0) ? (Y + rowb) : (X + rowb * FF + (c - 1));
        const int stride = (c == 0) ? 1 : FF;
        const float own = p[n * stride];
        float a = 0.f;
#pragma unroll
        for (int kE = 0; kE < DEG; ++kE) a += w_s[kE] * p[src_s[kE] * stride];
        unsigned short h1, l1, h2, l2;
        split_bf16(a, h1, l1); split_bf16(own, h2, l2);
        relA_hi[t * SREL + c] = h1;       relA_lo[t * SREL + c] = l1;       // agg
        relA_hi[t * SREL + 17 + c] = h2;  relA_lo[t * SREL + 17 + c] = l2;  // xn
        const int cf = (c == 0) ? 88 : (71 + c);                            // fc X/y cols
        fcA_hi[t * SFC + cf] = h2;        fcA_lo[t * SFC + cf] = l2;
    }
    __syncthreads();

    // rel: h = sigmoid([agg|xn] @ [W_rel;W_root] + b_rel) -> fcA cols 8..71
    {
        f32x4 acc[2] = {{0,0,0,0},{0,0,0,0}};
        gemm_frag(relA_hi, relA_lo, SREL, ws + OFF_REL, 64, 2, mycol, lr, lg, acc);
#pragma unroll
        for (int mt = 0; mt < 2; ++mt)
#pragma unroll
            for (int r = 0; r < 4; ++r) {
                const int row = mt * 16 + lg * 4 + r;
                if (row < TT) {
                    const float hv = 1.f / (1.f + __expf(-(acc[mt][r] + brel_v)));
                    unsigned short hi, lo; split_bf16(hv, hi, lo);
                    fcA_hi[row * SFC + 8 + mycol] = hi;
                    fcA_lo[row * SFC + 8 + mycol] = lo;
                }
            }
    }
    __syncthreads();

    // fc: z = feat[24][96] @ W_fc + b_fc -> zA (aliases relA)
    {
        f32x4 acc[2] = {{0,0,0,0},{0,0,0,0}};
        gemm_frag(fcA_hi, fcA_lo, SFC, ws + OFF_FC, 96, 3, mycol, lr, lg, acc);
#pragma unroll
        for (int mt = 0; mt < 2; ++mt)
#pragma unroll
            for (int r = 0; r < 4; ++r) {
                const int row = mt * 16 + lg * 4 + r;
                if (row < TT) {
                    unsigned short hi, lo; split_bf16(acc[mt][r] + bfc_v, hi, lo);
                    relA_hi[row * SREL + mycol] = hi;   // zA
                    relA_lo[row * SREL + mycol] = lo;
                }
            }
    }
    __syncthreads();

    // q,k,v = z @ W + b -> fp32 LDS [24][68]
    {
        const unsigned short* woffs[3] = { ws + OFF_Q, ws + OFF_K, ws + OFF_V };
        const float bias3[3] = { bq_v, bk_v, bv_v };
        float* dst3[3] = { qS, kS, vS };
#pragma unroll
        for (int m3 = 0; m3 < 3; ++m3) {
            f32x4 acc[2] = {{0,0,0,0},{0,0,0,0}};
            gemm_frag(relA_hi, relA_lo, SREL, woffs[m3], 64, 2, mycol, lr, lg, acc);
#pragma unroll
            for (int mt = 0; mt < 2; ++mt)
#pragma unroll
                for (int r = 0; r < 4; ++r) {
                    const int row = mt * 16 + lg * 4 + r;
                    if (row < TT) dst3[m3][row * 68 + mycol] = acc[mt][r] + bias3[m3];
                }
        }
    }
    __syncthreads();

    // scores: wave w = head w; sS aliases fcA (dead)
    for (int p2 = lane; p2 < TT * TT; p2 += 64) {
        const int r = p2 / TT, c2 = p2 - r * TT;
        float a = 0.f;
#pragma unroll
        for (int d4 = 0; d4 < 16; d4 += 4) {
            const float4 q4 = *(const float4*)&qS[r  * 68 + w * 16 + d4];
            const float4 k4 = *(const float4*)&kS[c2 * 68 + w * 16 + d4];
            a += q4.x * k4.x + q4.y * k4.y + q4.z * k4.z + q4.w * k4.w;
        }
        sS[w * 600 + r * 25 + c2] = a * 0.25f;
    }
    __syncthreads();

    // softmax (96 rows)
    if (tid < 4 * TT) {
        const int hh = tid / TT, r = tid - hh * TT;
        float* row = sS + hh * 600 + r * 25;
        float mx = row[0];
        for (int i2 = 1; i2 < TT; ++i2) mx = fmaxf(mx, row[i2]);
        float sm = 0.f;
        for (int i2 = 0; i2 < TT; ++i2) { const float ev = __expf(row[i2] - mx); row[i2] = ev; sm += ev; }
        const float inv = 1.f / sm;
        for (int i2 = 0; i2 < TT; ++i2) row[i2] *= inv;
    }
    __syncthreads();

    // ctx[t][j] = sum_jj s[j>>4][t][jj] * v[jj][j] -> ctxA bf16 (aliases zA/relA)
    {
        const int j = lane, hh = j >> 4;
        float acc6[6];
#pragma unroll
        for (int i = 0; i < 6; ++i) acc6[i] = 0.f;
        for (int jj = 0; jj < TT; ++jj) {
            const float vv = vS[jj * 68 + j];
#pragma unroll
            for (int i = 0; i < 6; ++i)
                acc6[i] += sS[hh * 600 + (w + 4 * i) * 25 + jj] * vv;
        }
#pragma unroll
        for (int i = 0; i < 6; ++i) {
            const int t = w + 4 * i;
            unsigned short hi, lo; split_bf16(acc6[i], hi, lo);
            relA_hi[t * SREL + j] = hi;
            relA_lo[t * SREL + j] = lo;
        }
    }
    __syncthreads();

    // o = ctx @ Wo + bo -> oA (aliases fcA/sS region)
    {
        f32x4 acc[2] = {{0,0,0,0},{0,0,0,0}};
        gemm_frag(relA_hi, relA_lo, SREL, ws + OFF_O, 64, 2, mycol, lr, lg, acc);
#pragma unroll
        for (int mt = 0; mt < 2; ++mt)
#pragma unroll
            for (int r = 0; r < 4; ++r) {
                const int row = mt * 16 + lg * 4 + r;
                if (row < TT) {
                    unsigned short hi, lo; split_bf16(acc[mt][r] + bo_v, hi, lo);
                    oA_hi[row * SREL + mycol] = hi;
                    oA_lo[row * SREL + mycol] = lo;
                }
            }
    }
    __syncthreads();

    // out = o @ W_mlp + b_mlp -> global
    {
        f32x4 acc[2] = {{0,0,0,0},{0,0,0,0}};
        gemm_frag(oA_hi, oA_lo, SREL, ws + OFF_M, 64, 2, mycol, lr, lg, acc);
#pragma unroll
        for (int mt = 0; mt < 2; ++mt)
#pragma unroll
            for (int r = 0; r < 4; ++r) {
                const int row = mt * 16 + lg * 4 + r;
                if (row < TT)
                    out[((size_t)(b * TT + row) * NN + n) * HID + mycol] = acc[mt][r] + bm_v;
            }
    }
}

extern "C" void kernel_launch(void* const* d_in, const int* in_sizes, int n_in,
                              void* d_out, int out_size, void* d_ws, size_t ws_size,
                              hipStream_t stream)
{
    const float* X     = (const float*)d_in[0];
    const float* Y     = (const float*)d_in[1];
    const int*   esrc  = (const int*)d_in[2];
    const float* ew    = (const float*)d_in[4];
    const float* pos   = (const float*)d_in[5];
    const float* W_rel = (const float*)d_in[6];
    const float* b_rel = (const float*)d_in[7];
    const float* W_root= (const float*)d_in[8];
    const float* W_fc  = (const float*)d_in[9];
    const float* b_fc  = (const float*)d_in[10];
    const float* Wq    = (const float*)d_in[11];
    const float* bq    = (const float*)d_in[12];
    const float* Wk    = (const float*)d_in[13];
    const float* bk    = (const float*)d_in[14];
    const float* Wv    = (const float*)d_in[15];
    const float* bv    = (const float*)d_in[16];
    const float* Wo    = (const float*)d_in[17];
    const float* bo    = (const float*)d_in[18];
    const float* Wm    = (const float*)d_in[19];
    const float* bm    = (const float*)d_in[20];
    float* out = (float*)d_out;
    unsigned short* ws = (unsigned short*)d_ws;

    prep_w<<<dim3(120), dim3(256), 0, stream>>>(W_rel, W_root, W_fc, Wq, Wk, Wv, Wo, Wm, ws);
    encoder_mfma<<<dim3(BB * NN), dim3(256), 0, stream>>>(
        X, Y, esrc, ew, pos, b_rel, b_fc, bq, bk, bv, bo, bm, ws, out);
}